// Round 7
// baseline (272.448 us; speedup 1.0000x reference)
//
#include <hip/hip_runtime.h>
#include <cmath>

#define CIN   512
#define COUT  64
#define DBINS 41
#define NFEAT 105   // DBINS + COUT
#define HF    16
#define WF    44
#define NPIX  704   // HF*WF
#define NCAM  24    // B*N
#define NXG   128
#define NVOX  16384 // 128*128 (NX2 == 1)
#define ROWF  210   // per-pixel feat row
#define BEVOF 146   // row tail offset: 64-float BEV accumulator per voxel
#define NPAIR (NCAM * NPIX * DBINS)  // 692736

// Workspace layout (bytes) — identical to rounds 4-6 (validated size):
#define WS_FEAT 8192
#define WS_CNT  14200832
#define WS_OFFS 14266368
#define WS_REC  14331904

// ---------------------------------------------------------------- utilities
__device__ __forceinline__ void inv3(const double a[9], double o[9]) {
    double c00 =  a[4]*a[8] - a[5]*a[7];
    double c01 = -(a[3]*a[8] - a[5]*a[6]);
    double c02 =  a[3]*a[7] - a[4]*a[6];
    double det = a[0]*c00 + a[1]*c01 + a[2]*c02;
    double id  = 1.0 / det;
    o[0] = c00 * id;
    o[1] = -(a[1]*a[8] - a[2]*a[7]) * id;
    o[2] =  (a[1]*a[5] - a[2]*a[4]) * id;
    o[3] = c01 * id;
    o[4] =  (a[0]*a[8] - a[2]*a[6]) * id;
    o[5] = -(a[0]*a[5] - a[2]*a[3]) * id;
    o[6] = c02 * id;
    o[7] = -(a[0]*a[7] - a[1]*a[6]) * id;
    o[8] =  (a[0]*a[4] - a[1]*a[3]) * id;
}

// --------------------------------------------------------- per-camera setup
__global__ void setup_cams_k(const float* __restrict__ rots,
                             const float* __restrict__ trans,
                             const float* __restrict__ intrins,
                             const float* __restrict__ post_rots,
                             const float* __restrict__ post_trans,
                             double* __restrict__ cams) {
    int i = blockIdx.x * blockDim.x + threadIdx.x;
    if (i >= NCAM) return;
    double R[9], K[9], PR[9], Kinv[9], PRinv[9];
    for (int k = 0; k < 9; ++k) {
        R[k]  = (double)rots[i*9 + k];
        K[k]  = (double)intrins[i*9 + k];
        PR[k] = (double)post_rots[i*9 + k];
    }
    inv3(K, Kinv);
    inv3(PR, PRinv);
    double* o = cams + (size_t)i * 24;
    for (int k = 0; k < 9; ++k) o[k] = PRinv[k];
    o[9]  = (double)post_trans[i*3 + 0];
    o[10] = (double)post_trans[i*3 + 1];
    o[11] = (double)post_trans[i*3 + 2];
    for (int r = 0; r < 3; ++r)
        for (int c = 0; c < 3; ++c)
            o[12 + r*3 + c] = R[r*3+0]*Kinv[0*3+c] + R[r*3+1]*Kinv[1*3+c] + R[r*3+2]*Kinv[2*3+c];
    o[21] = (double)trans[i*3 + 0];
    o[22] = (double)trans[i*3 + 1];
    o[23] = (double)trans[i*3 + 2];
}

// --------------------------------------------------------------- 1x1 conv GEMM
// x staged in LDS (reg-pipelined). w read from GLOBAL with wave-uniform
// addresses (scalar-load path) — removes 14/15 of the LDS reads per step.
// FMA order identical to rounds 5/6 -> bitwise-identical feat.
__global__ __launch_bounds__(512) void gemm_feat_k(const float* __restrict__ x,
                                                   const float* __restrict__ w,
                                                   const float* __restrict__ bias,
                                                   float* __restrict__ feat) {
    __shared__ float xs[16][64][4];   // 16 KB
    __shared__ float wsm[64 * 113];   // epilogue transpose buffer only

    int bx   = blockIdx.x;
    int kh   = bx & 1;
    int tile = bx >> 1;
    int bn   = tile / 11;
    int p0   = (tile - bn * 11) * 64;
    int lane = threadIdx.x & 63;
    int wid  = threadIdx.x >> 6;

    // wave-uniform output-group base; wave 7 overlaps back to 91..104 so all
    // 14 rows are in-bounds (overlap rows compute identical values).
    int obase = __builtin_amdgcn_readfirstlane((wid == 7) ? (NFEAT - 14) : wid * 14);

    // x staging coordinates
    int px  = threadIdx.x & 63;
    int kq0 = threadIdx.x >> 6;          // stages kq0 and kq0+8

    const float* gx = x + ((size_t)bn * CIN + kh * 256 + (kq0 << 2)) * NPIX + p0 + px;

    float xr[8];
    auto loadX = [&](int kt) {
        const float* g = gx + (size_t)kt * 64 * NPIX;
        #pragma unroll
        for (int j = 0; j < 4; ++j) xr[j]     = g[(size_t)j * NPIX];
        #pragma unroll
        for (int j = 0; j < 4; ++j) xr[4 + j] = g[(size_t)(32 + j) * NPIX];
    };

    float acc[14];
    #pragma unroll
    for (int i = 0; i < 14; ++i) acc[i] = 0.0f;

    loadX(0);

    for (int kt = 0; kt < 4; ++kt) {
        if (kt) __syncthreads();
        #pragma unroll
        for (int j = 0; j < 4; ++j) xs[kq0][px][j]     = xr[j];
        #pragma unroll
        for (int j = 0; j < 4; ++j) xs[kq0 + 8][px][j] = xr[4 + j];
        __syncthreads();
        if (kt < 3) loadX(kt + 1);
        // wave-uniform w base for this kt
        const float* wb = w + (size_t)obase * CIN + kh * 256 + kt * 64;
        #pragma unroll 4
        for (int kq = 0; kq < 16; ++kq) {
            float4 xv = *reinterpret_cast<const float4*>(&xs[kq][lane][0]);
            #pragma unroll
            for (int i = 0; i < 14; ++i) {
                float4 wv = *reinterpret_cast<const float4*>(wb + (size_t)i * CIN + (kq << 2));
                acc[i] = fmaf(xv.x, wv.x, acc[i]);
                acc[i] = fmaf(xv.y, wv.y, acc[i]);
                acc[i] = fmaf(xv.z, wv.z, acc[i]);
                acc[i] = fmaf(xv.w, wv.w, acc[i]);
            }
        }
    }
    __syncthreads();

    // epilogue: padded LDS transpose (overlap rows store identical values)
    #pragma unroll
    for (int i = 0; i < 14; ++i) {
        int o = obase + i;
        float b = (kh == 0) ? bias[o] : 0.0f;
        wsm[lane * 113 + o] = acc[i] + b;
    }
    __syncthreads();
    float* dst = feat + ((size_t)bn * NPIX + p0) * ROWF + kh * NFEAT;
    for (int idx = threadIdx.x; idx < 64 * NFEAT; idx += 512) {
        int pxx = idx / NFEAT;
        int o   = idx - pxx * NFEAT;
        dst[(size_t)pxx * ROWF + o] = wsm[pxx * 113 + o];
    }
}

// -------------------------------------------- softmax + geometry, in-place
// 4 independent waves per block, one pixel per wave (identical per-wave code).
__global__ __launch_bounds__(256) void phaseA_k(float* __restrict__ feat,
                                                const double* __restrict__ cams,
                                                int* __restrict__ cnt) {
    int wid  = threadIdx.x >> 6;
    int lane = threadIdx.x & 63;
    int pix  = blockIdx.x * 4 + wid;
    int bn   = pix / NPIX;
    int p    = pix - bn * NPIX;
    int h    = p / WF;
    int wpx  = p - h * WF;

    __shared__ float f[4][NFEAT];
    float* row = feat + (size_t)pix * ROWF;
    for (int o = lane; o < NFEAT; o += 64) f[wid][o] = row[o] + row[NFEAT + o];
    __syncthreads();

    float v = (lane < DBINS) ? f[wid][lane] : -1e30f;
    float m = v;
    #pragma unroll
    for (int o = 32; o > 0; o >>= 1) m = fmaxf(m, __shfl_xor(m, o, 64));
    float e = (lane < DBINS) ? expf(v - m) : 0.0f;
    float s = e;
    #pragma unroll
    for (int o = 32; o > 0; o >>= 1) s += __shfl_xor(s, o, 64);

    if (lane < DBINS) {
        float pd = e / s;
        const double* cm = cams + (size_t)bn * 24;
        double dd = 4.0 + (double)lane;
        double ax = (double)wpx - cm[9];
        double ay = (double)h   - cm[10];
        double az = dd          - cm[11];
        double q0 = cm[0]*ax + cm[1]*ay + cm[2]*az;
        double q1 = cm[3]*ax + cm[4]*ay + cm[5]*az;
        double q2 = cm[6]*ax + cm[7]*ay + cm[8]*az;
        double r0 = q0 * q2, r1 = q1 * q2, r2 = q2;
        double sx = cm[12]*r0 + cm[13]*r1 + cm[14]*r2 + cm[21];
        double sy = cm[15]*r0 + cm[16]*r1 + cm[17]*r2 + cm[22];
        double sz = cm[18]*r0 + cm[19]*r1 + cm[20]*r2 + cm[23];
        int cx = (int)((sx + 50.8) / 0.8);   // trunc == .astype(int32)
        int cy = (int)((sy + 50.8) / 0.8);
        int cz = (int)(sz / 20.0);
        bool ok = (cx >= 0) && (cx < NXG) && (cy >= 0) && (cy < NXG) && (cz == 0);
        int rk = ok ? (cy * NXG + cx) : -1;
        row[64 + lane] = pd;
        ((int*)row)[105 + lane] = rk;
        if (rk >= 0) atomicAdd(&cnt[rk], 1);
    }
    row[lane] = f[wid][DBINS + lane];
    row[BEVOF + lane] = 0.0f;
}

// ------------------------------------------------- exclusive scan of cnt
__global__ __launch_bounds__(1024) void scan_k(const int* __restrict__ cnt,
                                               int* __restrict__ offs) {
    __shared__ int sc[1024];
    int t = threadIdx.x;
    int loc[16];
    int s = 0;
    #pragma unroll
    for (int j = 0; j < 16; ++j) { loc[j] = cnt[t*16 + j]; s += loc[j]; }
    sc[t] = s;
    __syncthreads();
    for (int off = 1; off < 1024; off <<= 1) {
        int add = (t >= off) ? sc[t - off] : 0;
        __syncthreads();
        sc[t] += add;
        __syncthreads();
    }
    int base = sc[t] - s;
    #pragma unroll
    for (int j = 0; j < 16; ++j) { offs[t*16 + j] = base; base += loc[j]; }
}

// ------------------------------------------------- place pairs into segments
__global__ __launch_bounds__(256) void place_k(const float* __restrict__ feat,
                                               int* __restrict__ offs,
                                               unsigned* __restrict__ rec) {
    int i = blockIdx.x * 256 + threadIdx.x;
    if (i >= NPAIR) return;
    int pix = i / DBINS;
    int d   = i - pix * DBINS;
    const int* rowI = (const int*)(feat + (size_t)pix * ROWF);
    int r = rowI[105 + d];
    if (r >= 0) {
        int pos = atomicAdd(&offs[r], 1);
        rec[pos] = ((unsigned)pix << 6) | (unsigned)d;
    }
}

// ------------------------------------- entry-parallel segmented combine
__global__ __launch_bounds__(256) void combine_k(float* __restrict__ feat,
                                                 const int* __restrict__ offs,
                                                 const unsigned* __restrict__ rec) {
    int ncnt = offs[NVOX - 1];
    int lane = threadIdx.x & 63;
    int wave = (blockIdx.x << 2) + (threadIdx.x >> 6);
    int nwav = gridDim.x << 2;
    int nchunk = (ncnt + 31) >> 5;

    for (int ch = wave; ch < nchunk; ch += nwav) {
        int i0 = ch << 5;
        int n  = min(32, ncnt - i0);
        int   rv = -1, pv = 0;
        float wv = 0.0f;
        if (lane < n) {
            unsigned e = rec[i0 + lane];
            pv = (int)(e >> 6);
            int d = (int)(e & 63u);
            const float* row = feat + (size_t)pv * ROWF;
            rv = ((const int*)row)[105 + d];
            wv = row[64 + d];
        }
        float acc = 0.0f;
        if (n == 32) {
            float xv[32];
            #pragma unroll
            for (int j = 0; j < 32; ++j) {
                int pj = __shfl(pv, j, 64);
                xv[j] = feat[(size_t)pj * ROWF + lane];
            }
            #pragma unroll
            for (int j = 0; j < 32; ++j) {
                int   rj = __shfl(rv, j, 64);
                float wj = __shfl(wv, j, 64);
                acc = fmaf(wj, xv[j], acc);
                int rn = __shfl(rv, (j + 1) & 31, 64);
                if (j == 31 || rn != rj) {
                    atomicAdd(&feat[(size_t)rj * ROWF + BEVOF + lane], acc);
                    acc = 0.0f;
                }
            }
        } else {
            for (int j = 0; j < n; ++j) {
                int   rj = __shfl(rv, j, 64);
                float wj = __shfl(wv, j, 64);
                int   pj = __shfl(pv, j, 64);
                acc = fmaf(wj, feat[(size_t)pj * ROWF + lane], acc);
                int rn = __shfl(rv, (j + 1) & 31, 64);
                if (j == n - 1 || rn != rj) {
                    atomicAdd(&feat[(size_t)rj * ROWF + BEVOF + lane], acc);
                    acc = 0.0f;
                }
            }
        }
    }
}

// -------------------------------------------------------- bev tails -> out
__global__ __launch_bounds__(256) void transpose_k(const float* __restrict__ feat,
                                                   float* __restrict__ out) {
    __shared__ float t[64][65];
    int r0 = blockIdx.x * 64;
    int c  = threadIdx.x & 63;
    int r4 = threadIdx.x >> 6;
    #pragma unroll
    for (int i = 0; i < 16; ++i) {
        int r = r4 + i * 4;
        t[r][c] = feat[(size_t)(r0 + r) * ROWF + BEVOF + c];
    }
    __syncthreads();
    int rl  = threadIdx.x & 63;
    int cc0 = threadIdx.x >> 6;
    #pragma unroll
    for (int i = 0; i < 16; ++i) {
        int ch = cc0 + i * 4;
        out[(size_t)ch * NVOX + r0 + rl] = t[rl][ch];
    }
}

// --------------------------------------------------------------------- launch
extern "C" void kernel_launch(void* const* d_in, const int* in_sizes, int n_in,
                              void* d_out, int out_size, void* d_ws, size_t ws_size,
                              hipStream_t stream) {
    const float* img   = (const float*)d_in[0];
    const float* dw    = (const float*)d_in[1];
    const float* db    = (const float*)d_in[2];
    const float* rots  = (const float*)d_in[3];
    const float* trans = (const float*)d_in[4];
    const float* intr  = (const float*)d_in[5];
    const float* prot  = (const float*)d_in[6];
    const float* ptrn  = (const float*)d_in[7];
    float* out = (float*)d_out;

    char* ws = (char*)d_ws;
    double*   cams = (double*)ws;
    float*    feat = (float*)(ws + WS_FEAT);
    int*      cnt  = (int*)(ws + WS_CNT);
    int*      offs = (int*)(ws + WS_OFFS);
    unsigned* rec  = (unsigned*)(ws + WS_REC);

    hipMemsetAsync(cnt, 0, NVOX * sizeof(int), stream);
    setup_cams_k<<<1, 64, 0, stream>>>(rots, trans, intr, prot, ptrn, cams);
    gemm_feat_k<<<528, 512, 0, stream>>>(img, dw, db, feat);
    phaseA_k<<<NCAM * NPIX / 4, 256, 0, stream>>>(feat, cams, cnt);
    scan_k<<<1, 1024, 0, stream>>>(cnt, offs);
    place_k<<<(NPAIR + 255) / 256, 256, 0, stream>>>(feat, offs, rec);
    combine_k<<<2048, 256, 0, stream>>>(feat, offs, rec);
    transpose_k<<<NVOX / 64, 256, 0, stream>>>(feat, out);
}

// Round 8
// 254.028 us; speedup vs baseline: 1.0725x; 1.0725x over previous
//
#include <hip/hip_runtime.h>
#include <cmath>

#define CIN   512
#define COUT  64
#define DBINS 41
#define NFEAT 105   // DBINS + COUT
#define HF    16
#define WF    44
#define NPIX  704   // HF*WF
#define NCAM  24    // B*N
#define NXG   128
#define NVOX  16384 // 128*128 (NX2 == 1)
#define ROWF  210   // per-pixel feat row
#define BEVOF 146   // row tail offset: 64-float BEV accumulator per voxel
#define NPAIR (NCAM * NPIX * DBINS)  // 692736

// Workspace layout (bytes) — identical to rounds 4-7 (validated size):
#define WS_FEAT 8192
#define WS_CNT  14200832
#define WS_OFFS 14266368
#define WS_REC  14331904

// ---------------------------------------------------------------- utilities
__device__ __forceinline__ void inv3(const double a[9], double o[9]) {
    double c00 =  a[4]*a[8] - a[5]*a[7];
    double c01 = -(a[3]*a[8] - a[5]*a[6]);
    double c02 =  a[3]*a[7] - a[4]*a[6];
    double det = a[0]*c00 + a[1]*c01 + a[2]*c02;
    double id  = 1.0 / det;
    o[0] = c00 * id;
    o[1] = -(a[1]*a[8] - a[2]*a[7]) * id;
    o[2] =  (a[1]*a[5] - a[2]*a[4]) * id;
    o[3] = c01 * id;
    o[4] =  (a[0]*a[8] - a[2]*a[6]) * id;
    o[5] = -(a[0]*a[5] - a[2]*a[3]) * id;
    o[6] = c02 * id;
    o[7] = -(a[0]*a[7] - a[1]*a[6]) * id;
    o[8] =  (a[0]*a[4] - a[1]*a[3]) * id;
}

// --------------------------------------------------------- per-camera setup
__global__ void setup_cams_k(const float* __restrict__ rots,
                             const float* __restrict__ trans,
                             const float* __restrict__ intrins,
                             const float* __restrict__ post_rots,
                             const float* __restrict__ post_trans,
                             double* __restrict__ cams) {
    int i = blockIdx.x * blockDim.x + threadIdx.x;
    if (i >= NCAM) return;
    double R[9], K[9], PR[9], Kinv[9], PRinv[9];
    for (int k = 0; k < 9; ++k) {
        R[k]  = (double)rots[i*9 + k];
        K[k]  = (double)intrins[i*9 + k];
        PR[k] = (double)post_rots[i*9 + k];
    }
    inv3(K, Kinv);
    inv3(PR, PRinv);
    double* o = cams + (size_t)i * 24;
    for (int k = 0; k < 9; ++k) o[k] = PRinv[k];
    o[9]  = (double)post_trans[i*3 + 0];
    o[10] = (double)post_trans[i*3 + 1];
    o[11] = (double)post_trans[i*3 + 2];
    for (int r = 0; r < 3; ++r)
        for (int c = 0; c < 3; ++c)
            o[12 + r*3 + c] = R[r*3+0]*Kinv[0*3+c] + R[r*3+1]*Kinv[1*3+c] + R[r*3+2]*Kinv[2*3+c];
    o[21] = (double)trans[i*3 + 0];
    o[22] = (double)trans[i*3 + 1];
    o[23] = (double)trans[i*3 + 2];
}

// --------------------------------------------------------------- 1x1 conv GEMM
// Tile: M=256 px x N=56 outs, 8 waves, 4 px x 7 outs per thread.
// Per 4-k step: 4 lane b128 (x) + 7 broadcast b128 (w) per 224 FMAs.
// Grid = 66 px-tiles x 2 out-halves x 2 kh = 264 blocks.
// k-order identical to prior rounds -> bitwise-identical feat.
__global__ __launch_bounds__(512) void gemm_feat_k(const float* __restrict__ x,
                                                   const float* __restrict__ w,
                                                   const float* __restrict__ bias,
                                                   float* __restrict__ feat) {
    __shared__ float smem[256 * 57];          // 58,368 B
    float* xs = smem;                         // [8 kq][256 px][4]  = 8192 floats
    float* ws = smem + 8192;                  // [56 o][32 k]       = 1792 floats

    int bx   = blockIdx.x;                    // 0..263
    int kh   = bx & 1;
    int oh   = (bx >> 1) & 1;
    int tile = bx >> 2;                       // 0..65
    int p0g  = tile * 256;                    // flat pixel base (may span cams)
    int lane = threadIdx.x & 63;
    int wid  = threadIdx.x >> 6;              // 0..7
    int obase0 = oh * 49;                     // 0..55 or 49..104 (overlap rows identical)
    int og   = obase0 + wid * 7;              // wave's 7 outputs

    // x staging coords (fixed per thread): one int-div for the cam split
    int spx  = threadIdx.x & 255;
    int skq  = (threadIdx.x >> 8) * 4;        // 0 or 4
    int gpix = p0g + spx;
    int sbn  = gpix / NPIX;
    int sp   = gpix - sbn * NPIX;
    const float* gx = x + ((size_t)sbn * CIN + kh * 256) * NPIX + sp;

    // w staging coords
    int wo  = threadIdx.x >> 3;               // 0..63 (only <56 stage)
    int wci = (threadIdx.x & 7) << 2;

    float acc[7][4];
    #pragma unroll
    for (int i = 0; i < 7; ++i)
        #pragma unroll
        for (int j = 0; j < 4; ++j) acc[i][j] = 0.0f;

    for (int kt = 0; kt < 8; ++kt) {          // BK=32, K=256 per kh half
        if (kt) __syncthreads();
        // ---- stage x: 4 float4 per thread, b128 LDS stores
        #pragma unroll
        for (int j = 0; j < 4; ++j) {
            int kq = skq + j;
            const float* g = gx + (size_t)(kt * 32 + kq * 4) * NPIX;
            float4 v;
            v.x = g[0];
            v.y = g[(size_t)NPIX];
            v.z = g[(size_t)2 * NPIX];
            v.w = g[(size_t)3 * NPIX];
            *reinterpret_cast<float4*>(&xs[(kq * 256 + spx) * 4]) = v;
        }
        // ---- stage w: 448 threads, 1 float4 each
        if (wo < 56) {
            const float* gw = w + (size_t)(obase0 + wo) * CIN + kh * 256 + kt * 32 + wci;
            *reinterpret_cast<float4*>(&ws[wo * 32 + wci]) = *reinterpret_cast<const float4*>(gw);
        }
        __syncthreads();
        // ---- compute: 8 kq steps of 4 k each
        #pragma unroll
        for (int kq = 0; kq < 8; ++kq) {
            float4 xv[4];
            #pragma unroll
            for (int j = 0; j < 4; ++j)
                xv[j] = *reinterpret_cast<const float4*>(&xs[(kq * 256 + lane + j * 64) * 4]);
            #pragma unroll
            for (int i = 0; i < 7; ++i) {
                float4 wv = *reinterpret_cast<const float4*>(&ws[(wid * 7 + i) * 32 + (kq << 2)]);
                #pragma unroll
                for (int j = 0; j < 4; ++j) {
                    acc[i][j] = fmaf(xv[j].x, wv.x, acc[i][j]);
                    acc[i][j] = fmaf(xv[j].y, wv.y, acc[i][j]);
                    acc[i][j] = fmaf(xv[j].z, wv.z, acc[i][j]);
                    acc[i][j] = fmaf(xv[j].w, wv.w, acc[i][j]);
                }
            }
        }
    }
    __syncthreads();

    // ---- epilogue: LDS transpose tile [256][57] (57 coprime 32 -> conflict-free)
    #pragma unroll
    for (int i = 0; i < 7; ++i) {
        float b = (kh == 0) ? bias[og + i] : 0.0f;
        #pragma unroll
        for (int j = 0; j < 4; ++j)
            smem[(lane + j * 64) * 57 + wid * 7 + i] = acc[i][j] + b;
    }
    __syncthreads();
    for (int idx = threadIdx.x; idx < 256 * 56; idx += 512) {
        int px = idx / 56;
        int ol = idx - px * 56;
        feat[(size_t)(p0g + px) * ROWF + kh * NFEAT + obase0 + ol] = smem[px * 57 + ol];
    }
}

// -------------------------------------------- softmax + geometry, in-place
// 4 independent waves per block, one pixel per wave.
__global__ __launch_bounds__(256) void phaseA_k(float* __restrict__ feat,
                                                const double* __restrict__ cams,
                                                int* __restrict__ cnt) {
    int wid  = threadIdx.x >> 6;
    int lane = threadIdx.x & 63;
    int pix  = blockIdx.x * 4 + wid;
    int bn   = pix / NPIX;
    int p    = pix - bn * NPIX;
    int h    = p / WF;
    int wpx  = p - h * WF;

    __shared__ float f[4][NFEAT];
    float* row = feat + (size_t)pix * ROWF;
    for (int o = lane; o < NFEAT; o += 64) f[wid][o] = row[o] + row[NFEAT + o];
    __syncthreads();

    float v = (lane < DBINS) ? f[wid][lane] : -1e30f;
    float m = v;
    #pragma unroll
    for (int o = 32; o > 0; o >>= 1) m = fmaxf(m, __shfl_xor(m, o, 64));
    float e = (lane < DBINS) ? expf(v - m) : 0.0f;
    float s = e;
    #pragma unroll
    for (int o = 32; o > 0; o >>= 1) s += __shfl_xor(s, o, 64);

    if (lane < DBINS) {
        float pd = e / s;
        const double* cm = cams + (size_t)bn * 24;
        double dd = 4.0 + (double)lane;
        double ax = (double)wpx - cm[9];
        double ay = (double)h   - cm[10];
        double az = dd          - cm[11];
        double q0 = cm[0]*ax + cm[1]*ay + cm[2]*az;
        double q1 = cm[3]*ax + cm[4]*ay + cm[5]*az;
        double q2 = cm[6]*ax + cm[7]*ay + cm[8]*az;
        double r0 = q0 * q2, r1 = q1 * q2, r2 = q2;
        double sx = cm[12]*r0 + cm[13]*r1 + cm[14]*r2 + cm[21];
        double sy = cm[15]*r0 + cm[16]*r1 + cm[17]*r2 + cm[22];
        double sz = cm[18]*r0 + cm[19]*r1 + cm[20]*r2 + cm[23];
        int cx = (int)((sx + 50.8) / 0.8);   // trunc == .astype(int32)
        int cy = (int)((sy + 50.8) / 0.8);
        int cz = (int)(sz / 20.0);
        bool ok = (cx >= 0) && (cx < NXG) && (cy >= 0) && (cy < NXG) && (cz == 0);
        int rk = ok ? (cy * NXG + cx) : -1;
        row[64 + lane] = pd;
        ((int*)row)[105 + lane] = rk;
        if (rk >= 0) atomicAdd(&cnt[rk], 1);
    }
    row[lane] = f[wid][DBINS + lane];
    row[BEVOF + lane] = 0.0f;
}

// ------------------------------------------------- exclusive scan of cnt
__global__ __launch_bounds__(1024) void scan_k(const int* __restrict__ cnt,
                                               int* __restrict__ offs) {
    __shared__ int sc[1024];
    int t = threadIdx.x;
    int loc[16];
    int s = 0;
    #pragma unroll
    for (int j = 0; j < 16; ++j) { loc[j] = cnt[t*16 + j]; s += loc[j]; }
    sc[t] = s;
    __syncthreads();
    for (int off = 1; off < 1024; off <<= 1) {
        int add = (t >= off) ? sc[t - off] : 0;
        __syncthreads();
        sc[t] += add;
        __syncthreads();
    }
    int base = sc[t] - s;
    #pragma unroll
    for (int j = 0; j < 16; ++j) { offs[t*16 + j] = base; base += loc[j]; }
}

// ------------------------------------------------- place pairs into segments
__global__ __launch_bounds__(256) void place_k(const float* __restrict__ feat,
                                               int* __restrict__ offs,
                                               unsigned* __restrict__ rec) {
    int i = blockIdx.x * 256 + threadIdx.x;
    if (i >= NPAIR) return;
    int pix = i / DBINS;
    int d   = i - pix * DBINS;
    const int* rowI = (const int*)(feat + (size_t)pix * ROWF);
    int r = rowI[105 + d];
    if (r >= 0) {
        int pos = atomicAdd(&offs[r], 1);
        rec[pos] = ((unsigned)pix << 6) | (unsigned)d;
    }
}

// ------------------------------------- entry-parallel segmented combine
__global__ __launch_bounds__(256) void combine_k(float* __restrict__ feat,
                                                 const int* __restrict__ offs,
                                                 const unsigned* __restrict__ rec) {
    int ncnt = offs[NVOX - 1];
    int lane = threadIdx.x & 63;
    int wave = (blockIdx.x << 2) + (threadIdx.x >> 6);
    int nwav = gridDim.x << 2;
    int nchunk = (ncnt + 31) >> 5;

    for (int ch = wave; ch < nchunk; ch += nwav) {
        int i0 = ch << 5;
        int n  = min(32, ncnt - i0);
        int   rv = -1, pv = 0;
        float wv = 0.0f;
        if (lane < n) {
            unsigned e = rec[i0 + lane];
            pv = (int)(e >> 6);
            int d = (int)(e & 63u);
            const float* row = feat + (size_t)pv * ROWF;
            rv = ((const int*)row)[105 + d];
            wv = row[64 + d];
        }
        float acc = 0.0f;
        if (n == 32) {
            float xv[32];
            #pragma unroll
            for (int j = 0; j < 32; ++j) {
                int pj = __shfl(pv, j, 64);
                xv[j] = feat[(size_t)pj * ROWF + lane];
            }
            #pragma unroll
            for (int j = 0; j < 32; ++j) {
                int   rj = __shfl(rv, j, 64);
                float wj = __shfl(wv, j, 64);
                acc = fmaf(wj, xv[j], acc);
                int rn = __shfl(rv, (j + 1) & 31, 64);
                if (j == 31 || rn != rj) {
                    atomicAdd(&feat[(size_t)rj * ROWF + BEVOF + lane], acc);
                    acc = 0.0f;
                }
            }
        } else {
            for (int j = 0; j < n; ++j) {
                int   rj = __shfl(rv, j, 64);
                float wj = __shfl(wv, j, 64);
                int   pj = __shfl(pv, j, 64);
                acc = fmaf(wj, feat[(size_t)pj * ROWF + lane], acc);
                int rn = __shfl(rv, (j + 1) & 31, 64);
                if (j == n - 1 || rn != rj) {
                    atomicAdd(&feat[(size_t)rj * ROWF + BEVOF + lane], acc);
                    acc = 0.0f;
                }
            }
        }
    }
}

// -------------------------------------------------------- bev tails -> out
__global__ __launch_bounds__(256) void transpose_k(const float* __restrict__ feat,
                                                   float* __restrict__ out) {
    __shared__ float t[64][65];
    int r0 = blockIdx.x * 64;
    int c  = threadIdx.x & 63;
    int r4 = threadIdx.x >> 6;
    #pragma unroll
    for (int i = 0; i < 16; ++i) {
        int r = r4 + i * 4;
        t[r][c] = feat[(size_t)(r0 + r) * ROWF + BEVOF + c];
    }
    __syncthreads();
    int rl  = threadIdx.x & 63;
    int cc0 = threadIdx.x >> 6;
    #pragma unroll
    for (int i = 0; i < 16; ++i) {
        int ch = cc0 + i * 4;
        out[(size_t)ch * NVOX + r0 + rl] = t[rl][ch];
    }
}

// --------------------------------------------------------------------- launch
extern "C" void kernel_launch(void* const* d_in, const int* in_sizes, int n_in,
                              void* d_out, int out_size, void* d_ws, size_t ws_size,
                              hipStream_t stream) {
    const float* img   = (const float*)d_in[0];
    const float* dw    = (const float*)d_in[1];
    const float* db    = (const float*)d_in[2];
    const float* rots  = (const float*)d_in[3];
    const float* trans = (const float*)d_in[4];
    const float* intr  = (const float*)d_in[5];
    const float* prot  = (const float*)d_in[6];
    const float* ptrn  = (const float*)d_in[7];
    float* out = (float*)d_out;

    char* ws = (char*)d_ws;
    double*   cams = (double*)ws;
    float*    feat = (float*)(ws + WS_FEAT);
    int*      cnt  = (int*)(ws + WS_CNT);
    int*      offs = (int*)(ws + WS_OFFS);
    unsigned* rec  = (unsigned*)(ws + WS_REC);

    hipMemsetAsync(cnt, 0, NVOX * sizeof(int), stream);
    setup_cams_k<<<1, 64, 0, stream>>>(rots, trans, intr, prot, ptrn, cams);
    gemm_feat_k<<<264, 512, 0, stream>>>(img, dw, db, feat);
    phaseA_k<<<NCAM * NPIX / 4, 256, 0, stream>>>(feat, cams, cnt);
    scan_k<<<1, 1024, 0, stream>>>(cnt, offs);
    place_k<<<(NPAIR + 255) / 256, 256, 0, stream>>>(feat, offs, rec);
    combine_k<<<2048, 256, 0, stream>>>(feat, offs, rec);
    transpose_k<<<NVOX / 64, 256, 0, stream>>>(feat, out);
}